// Round 1
// baseline (417.868 us; speedup 1.0000x reference)
//
#include <hip/hip_runtime.h>
#include <hip/hip_bf16.h>
#include <cstdint>

#define T_SEQ 2048
#define DIM   1024
#define NHEAD 16
#define NKVH  8
#define HDIM  64
#define QKVN  3584   // 2048 (q) + 1024 (k) + 512 (v)

static constexpr float LAMBDA_INIT_F = 0.3555090675909693f;
static constexpr float ONE_MINUS_LI  = 0.6444909324090307f;

typedef __bf16 bf16x8 __attribute__((ext_vector_type(8)));
typedef float  f32x4  __attribute__((ext_vector_type(4)));

static __device__ __forceinline__ ushort f2bf(float f) {
  union { float f; uint32_t u; } x; x.f = f;
  uint32_t u = x.u;
  uint32_t r = (u + 0x7fffu + ((u >> 16) & 1u)) >> 16;
  return (ushort)r;
}
static __device__ __forceinline__ float bf2f(ushort u) {
  union { uint32_t u; float f; } x; x.u = ((uint32_t)u) << 16; return x.f;
}
static __device__ __forceinline__ f32x4 zero4() {
  f32x4 z = {0.f, 0.f, 0.f, 0.f}; return z;
}
// Load one 8-element A/B fragment for mfma_f32_16x16x32_bf16.
// Per-lane k layout: two 4-element halves at k = 4*(lane>>4) and k = 16 + 4*(lane>>4).
// p points at element [row][4*(lane>>4)]; halves at p and p+16.
static __device__ __forceinline__ bf16x8 ldfrag(const ushort* p) {
  union { bf16x8 v; uint2 u[2]; } r;
  r.u[0] = *(const uint2*)(p);
  r.u[1] = *(const uint2*)(p + 16);
  return r.v;
}

// ---------------- elementwise prep ----------------
__global__ void cvt_bf16(const float* __restrict__ src, ushort* __restrict__ dst, int n) {
  int i = blockIdx.x * 256 + threadIdx.x;
  if (i < n) dst[i] = f2bf(src[i]);
}

__global__ void lam_kernel(const float* __restrict__ lq1, const float* __restrict__ lk1,
                           const float* __restrict__ lq2, const float* __restrict__ lk2,
                           float* __restrict__ lam) {
  int lane = threadIdx.x;  // 64 threads
  float p1 = lq1[lane] * lk1[lane];
  float p2 = lq2[lane] * lk2[lane];
  #pragma unroll
  for (int off = 32; off >= 1; off >>= 1) {
    p1 += __shfl_down(p1, off);
    p2 += __shfl_down(p2, off);
  }
  if (lane == 0) *lam = expf(p1) - expf(p2) + LAMBDA_INIT_F;
}

// ---------------- GEMM: C[M][N] = A[M][K] (bf16) @ W[N][K]^T (bf16) ----------------
// 128x128 tile, BK=32, 256 threads (4 waves), each wave a 64x64 quadrant.
template<int BF16OUT>
__global__ __launch_bounds__(256) void gemm_bt(const ushort* __restrict__ A,
                                               const ushort* __restrict__ W,
                                               void* __restrict__ Cout,
                                               int M, int N, int K) {
  __shared__ ushort As[128][40];
  __shared__ ushort Ws[128][40];
  const int tid  = threadIdx.x;
  const int lane = tid & 63;
  const int w    = tid >> 6;
  const int wr   = w >> 1, wc = w & 1;
  const int bm   = blockIdx.y * 128, bn = blockIdx.x * 128;
  const int fr   = lane & 15;
  const int fg   = (lane >> 4) * 4;

  f32x4 acc[4][4];
  #pragma unroll
  for (int m = 0; m < 4; ++m)
    #pragma unroll
    for (int n = 0; n < 4; ++n) acc[m][n] = zero4();

  const int lrow = tid >> 1;          // 0..127
  const int lcol = (tid & 1) * 16;    // 0 or 16
  const ushort* ag = A + (size_t)(bm + lrow) * K + lcol;
  const ushort* wg = W + (size_t)(bn + lrow) * K + lcol;

  for (int k0 = 0; k0 < K; k0 += 32) {
    uint4 a0 = *(const uint4*)(ag + k0);
    uint4 a1 = *(const uint4*)(ag + k0 + 8);
    uint4 w0 = *(const uint4*)(wg + k0);
    uint4 w1 = *(const uint4*)(wg + k0 + 8);
    __syncthreads();
    *(uint4*)&As[lrow][lcol]     = a0;
    *(uint4*)&As[lrow][lcol + 8] = a1;
    *(uint4*)&Ws[lrow][lcol]     = w0;
    *(uint4*)&Ws[lrow][lcol + 8] = w1;
    __syncthreads();
    bf16x8 af[4], bfr[4];
    #pragma unroll
    for (int m = 0; m < 4; ++m) af[m]  = ldfrag(&As[wr*64 + m*16 + fr][fg]);
    #pragma unroll
    for (int n = 0; n < 4; ++n) bfr[n] = ldfrag(&Ws[wc*64 + n*16 + fr][fg]);
    #pragma unroll
    for (int m = 0; m < 4; ++m)
      #pragma unroll
      for (int n = 0; n < 4; ++n)
        acc[m][n] = __builtin_amdgcn_mfma_f32_16x16x32_bf16(af[m], bfr[n], acc[m][n], 0, 0, 0);
  }

  #pragma unroll
  for (int m = 0; m < 4; ++m)
    #pragma unroll
    for (int n = 0; n < 4; ++n)
      #pragma unroll
      for (int i = 0; i < 4; ++i) {
        int row = bm + wr*64 + m*16 + fg + i;   // D row = (lane>>4)*4 + reg
        int col = bn + wc*64 + n*16 + fr;       // D col = lane&15
        float v = acc[m][n][i];
        if (BF16OUT) ((ushort*)Cout)[(size_t)row * N + col] = f2bf(v);
        else         ((float*)Cout)[(size_t)row * N + col]  = v;
      }
}

// ---------------- RoPE + relayout ----------------
// dst layout [2 comp][nheads][T][HDIM] bf16, RoPE applied (interleaved pairs).
__global__ void rope_pack(const ushort* __restrict__ QKV, ushort* __restrict__ dst,
                          const float* __restrict__ fc, const float* __restrict__ fs,
                          int nheads, int col_off, int total) {
  int idx = blockIdx.x * 256 + threadIdx.x;
  if (idx >= total) return;
  int per_t = nheads * 64;         // pairs per t: nheads * 2comp * 32pairs
  int t  = idx / per_t;
  int r  = idx - t * per_t;
  int h  = r >> 6;
  int c2 = (r >> 5) & 1;
  int j  = r & 31;
  int col = col_off + h * 2 * HDIM + c2 * HDIM + 2 * j;
  float rv = bf2f(QKV[(size_t)t * QKVN + col]);
  float iv = bf2f(QKV[(size_t)t * QKVN + col + 1]);
  float c = fc[t * 32 + j], s = fs[t * 32 + j];
  float orr = rv * c - iv * s;
  float oi  = rv * s + iv * c;
  size_t o = ((size_t)(c2 * nheads + h) * T_SEQ + t) * HDIM + 2 * j;
  dst[o]     = f2bf(orr);
  dst[o + 1] = f2bf(oi);
}

// V transposed: Vt[kh*64+d][T]
__global__ void pack_v(const ushort* __restrict__ QKV, ushort* __restrict__ Vt) {
  int idx = blockIdx.x * 256 + threadIdx.x;   // < 512*2048
  int t = idx & (T_SEQ - 1);
  int rest = idx >> 11;                        // kh*64 + d
  Vt[(size_t)rest * T_SEQ + t] = QKV[(size_t)t * QKVN + 3072 + rest];
}

// ---------------- flash attention, 2 streams ----------------
__global__ __launch_bounds__(256) void attn_kernel(const ushort* __restrict__ Qr,
                                                   const ushort* __restrict__ Kr,
                                                   const ushort* __restrict__ Vt,
                                                   const float* __restrict__ lam_p,
                                                   float* __restrict__ Y) {
  const int qb  = blockIdx.x;   // 0..31
  const int h   = blockIdx.y;   // 0..15
  const int kh  = h >> 1;       // N_REP = 2
  const int tid = threadIdx.x;
  const int lane = tid & 63;
  const int w   = tid >> 6;     // wave: 16 q-rows each
  const int fr  = lane & 15;
  const int fg  = (lane >> 4) * 4;

  __shared__ ushort Qs[2][64][72];
  __shared__ ushort Ks[2][64][72];
  __shared__ ushort Vs[64][72];      // [d][s]
  __shared__ ushort Ps[2][64][72];

  {
    int row = tid >> 2, col = (tid & 3) * 16;
    #pragma unroll
    for (int c2 = 0; c2 < 2; ++c2) {
      const ushort* src = Qr + ((size_t)(c2 * NHEAD + h) * T_SEQ + qb * 64 + row) * HDIM + col;
      *(uint4*)&Qs[c2][row][col]     = *(const uint4*)src;
      *(uint4*)&Qs[c2][row][col + 8] = *(const uint4*)(src + 8);
    }
  }

  float m_[2][4], l_[2][4];
  f32x4 o_[2][4];
  #pragma unroll
  for (int st = 0; st < 2; ++st) {
    #pragma unroll
    for (int i = 0; i < 4; ++i) { m_[st][i] = -__builtin_inff(); l_[st][i] = 0.f; }
    #pragma unroll
    for (int dn = 0; dn < 4; ++dn) o_[st][dn] = zero4();
  }

  for (int kt = 0; kt <= qb; ++kt) {
    const int kvb = kt * 64;
    __syncthreads();
    {
      int row = tid >> 2, col = (tid & 3) * 16;
      #pragma unroll
      for (int c2 = 0; c2 < 2; ++c2) {
        const ushort* src = Kr + ((size_t)(c2 * NKVH + kh) * T_SEQ + kvb + row) * HDIM + col;
        *(uint4*)&Ks[c2][row][col]     = *(const uint4*)src;
        *(uint4*)&Ks[c2][row][col + 8] = *(const uint4*)(src + 8);
      }
      const ushort* vsrc = Vt + (size_t)(kh * 64 + row) * T_SEQ + kvb + col;
      *(uint4*)&Vs[row][col]     = *(const uint4*)vsrc;
      *(uint4*)&Vs[row][col + 8] = *(const uint4*)(vsrc + 8);
    }
    __syncthreads();

    // S = Q K^T for both streams; per wave 16 q-rows x 64 cols
    float sv[2][4][4];
    #pragma unroll
    for (int st = 0; st < 2; ++st)
      #pragma unroll
      for (int n = 0; n < 4; ++n) {
        f32x4 acc = zero4();
        #pragma unroll
        for (int ks = 0; ks < 2; ++ks) {
          bf16x8 aq = ldfrag(&Qs[st][w*16 + fr][ks*32 + fg]);
          bf16x8 bk = ldfrag(&Ks[st][n*16 + fr][ks*32 + fg]);
          acc = __builtin_amdgcn_mfma_f32_16x16x32_bf16(aq, bk, acc, 0, 0, 0);
        }
        #pragma unroll
        for (int i = 0; i < 4; ++i) sv[st][n][i] = acc[i];
      }

    const int row0 = qb*64 + w*16 + fg;
    #pragma unroll
    for (int st = 0; st < 2; ++st)
      #pragma unroll
      for (int n = 0; n < 4; ++n) {
        int colg = kvb + n*16 + fr;
        #pragma unroll
        for (int i = 0; i < 4; ++i) {
          float s = sv[st][n][i] * 0.125f;
          sv[st][n][i] = (colg <= row0 + i) ? s : -__builtin_inff();
        }
      }

    #pragma unroll
    for (int st = 0; st < 2; ++st) {
      float pv[4][4];
      #pragma unroll
      for (int i = 0; i < 4; ++i) {
        float mx = fmaxf(fmaxf(sv[st][0][i], sv[st][1][i]), fmaxf(sv[st][2][i], sv[st][3][i]));
        #pragma unroll
        for (int off = 1; off < 16; off <<= 1) mx = fmaxf(mx, __shfl_xor(mx, off));
        float mnew = fmaxf(m_[st][i], mx);
        float sc = __expf(m_[st][i] - mnew);   // first tile: exp(-inf)=0
        float rs = 0.f;
        #pragma unroll
        for (int n = 0; n < 4; ++n) { float p = __expf(sv[st][n][i] - mnew); pv[n][i] = p; rs += p; }
        #pragma unroll
        for (int off = 1; off < 16; off <<= 1) rs += __shfl_xor(rs, off);
        l_[st][i] = l_[st][i] * sc + rs;
        m_[st][i] = mnew;
        #pragma unroll
        for (int dn = 0; dn < 4; ++dn) o_[st][dn][i] *= sc;
      }
      #pragma unroll
      for (int n = 0; n < 4; ++n)
        #pragma unroll
        for (int i = 0; i < 4; ++i)
          Ps[st][w*16 + fg + i][n*16 + fr] = f2bf(pv[n][i]);
    }
    __syncthreads();

    // O += P @ V   (A = P [16xK], B = V via Vt tile [d][s])
    #pragma unroll
    for (int ks = 0; ks < 2; ++ks) {
      bf16x8 a1 = ldfrag(&Ps[0][w*16 + fr][ks*32 + fg]);
      bf16x8 a2 = ldfrag(&Ps[1][w*16 + fr][ks*32 + fg]);
      #pragma unroll
      for (int dn = 0; dn < 4; ++dn) {
        bf16x8 bv = ldfrag(&Vs[dn*16 + fr][ks*32 + fg]);
        o_[0][dn] = __builtin_amdgcn_mfma_f32_16x16x32_bf16(a1, bv, o_[0][dn], 0, 0, 0);
        o_[1][dn] = __builtin_amdgcn_mfma_f32_16x16x32_bf16(a2, bv, o_[1][dn], 0, 0, 0);
      }
    }
  }

  const float lam = *lam_p;
  #pragma unroll
  for (int dn = 0; dn < 4; ++dn)
    #pragma unroll
    for (int i = 0; i < 4; ++i) {
      int row = qb*64 + w*16 + fg + i;
      int col = h*64 + dn*16 + fr;
      float v = o_[0][dn][i] / l_[0][i] - lam * o_[1][dn][i] / l_[1][i];
      Y[(size_t)row * DIM + col] = v;
    }
}

// ---------------- per-head stats over (T, HD) ----------------
__global__ __launch_bounds__(256) void stats_kernel(const float* __restrict__ Y, float* __restrict__ stats) {
  int h = blockIdx.x;
  double s = 0.0, s2 = 0.0;
  for (int e = threadIdx.x; e < T_SEQ * HDIM; e += 256) {
    int t = e >> 6, d = e & 63;
    float v = Y[(size_t)t * DIM + h * 64 + d];
    s += v; s2 += (double)v * v;
  }
  #pragma unroll
  for (int off = 32; off >= 1; off >>= 1) { s += __shfl_down(s, off); s2 += __shfl_down(s2, off); }
  __shared__ double sb[8];
  int wv = threadIdx.x >> 6, lane = threadIdx.x & 63;
  if (lane == 0) { sb[wv] = s; sb[4 + wv] = s2; }
  __syncthreads();
  if (threadIdx.x == 0) {
    double S  = sb[0] + sb[1] + sb[2] + sb[3];
    double S2 = sb[4] + sb[5] + sb[6] + sb[7];
    const double N = (double)T_SEQ * HDIM;
    double mean = S / N;
    double var  = S2 / N - mean * mean;
    stats[h]      = (float)mean;
    stats[16 + h] = (float)(1.0 / sqrt(var + 1e-5));
  }
}

__global__ void norm_cvt(const float* __restrict__ Y, const float* __restrict__ stats,
                         ushort* __restrict__ Yb) {
  int idx = blockIdx.x * 256 + threadIdx.x;   // < T*DIM
  int col = idx & (DIM - 1);
  int h = col >> 6;
  float v = (Y[idx] - stats[h]) * stats[16 + h] * ONE_MINUS_LI;
  Yb[idx] = f2bf(v);
}

// ---------------- launch ----------------
extern "C" void kernel_launch(void* const* d_in, const int* in_sizes, int n_in,
                              void* d_out, int out_size, void* d_ws, size_t ws_size,
                              hipStream_t stream) {
  const float* x   = (const float*)d_in[0];
  const float* fc  = (const float*)d_in[1];
  const float* fs  = (const float*)d_in[2];
  const float* wq  = (const float*)d_in[3];
  const float* wk  = (const float*)d_in[4];
  const float* wv  = (const float*)d_in[5];
  const float* wo  = (const float*)d_in[6];
  const float* lq1 = (const float*)d_in[7];
  const float* lk1 = (const float*)d_in[8];
  const float* lq2 = (const float*)d_in[9];
  const float* lk2 = (const float*)d_in[10];
  float* out = (float*)d_out;

  char* ws = (char*)d_ws;
  const size_t OFF_XB   = 0;                         // 2048*1024 bf16
  const size_t OFF_WB   = OFF_XB  + 4194304;         // 3584*1024 bf16
  const size_t OFF_WOB  = OFF_WB  + 7340032;         // 1024*1024 bf16
  const size_t OFF_QKV  = OFF_WOB + 2097152;         // 2048*3584 bf16
  const size_t OFF_QR   = OFF_QKV + 14680064;        // 2*16*2048*64 bf16
  const size_t OFF_KR   = OFF_QR  + 8388608;         // 2*8*2048*64 bf16
  const size_t OFF_VT   = OFF_KR  + 4194304;         // 8*64*2048 bf16
  const size_t OFF_Y    = OFF_VT  + 2097152;         // 2048*1024 f32
  const size_t OFF_YB   = OFF_Y   + 8388608;         // 2048*1024 bf16
  const size_t OFF_ST   = OFF_YB  + 4194304;         // stats

  ushort* xb   = (ushort*)(ws + OFF_XB);
  ushort* Wb   = (ushort*)(ws + OFF_WB);
  ushort* Wob  = (ushort*)(ws + OFF_WOB);
  ushort* QKVb = (ushort*)(ws + OFF_QKV);
  ushort* Qr   = (ushort*)(ws + OFF_QR);
  ushort* Kr   = (ushort*)(ws + OFF_KR);
  ushort* Vt   = (ushort*)(ws + OFF_VT);
  float*  Yf   = (float*)(ws + OFF_Y);
  ushort* Yb   = (ushort*)(ws + OFF_YB);
  float*  stat = (float*)(ws + OFF_ST);
  float*  lamp = stat + 32;

  cvt_bf16<<<8192, 256, 0, stream>>>(x,  xb, 2097152);
  cvt_bf16<<<8192, 256, 0, stream>>>(wq, Wb, 2097152);
  cvt_bf16<<<4096, 256, 0, stream>>>(wk, Wb + 2048*1024, 1048576);
  cvt_bf16<<<2048, 256, 0, stream>>>(wv, Wb + 3072*1024, 524288);
  cvt_bf16<<<4096, 256, 0, stream>>>(wo, Wob, 1048576);
  lam_kernel<<<1, 64, 0, stream>>>(lq1, lk1, lq2, lk2, lamp);

  gemm_bt<1><<<dim3(QKVN/128, T_SEQ/128), 256, 0, stream>>>(xb, Wb, QKVb, T_SEQ, QKVN, DIM);

  rope_pack<<<8192, 256, 0, stream>>>(QKVb, Qr, fc, fs, NHEAD, 0,    2097152);
  rope_pack<<<4096, 256, 0, stream>>>(QKVb, Kr, fc, fs, NKVH,  2048, 1048576);
  pack_v<<<4096, 256, 0, stream>>>(QKVb, Vt);

  attn_kernel<<<dim3(T_SEQ/64, NHEAD), 256, 0, stream>>>(Qr, Kr, Vt, lamp, Yf);

  stats_kernel<<<16, 256, 0, stream>>>(Yf, stat);
  norm_cvt<<<8192, 256, 0, stream>>>(Yf, stat, Yb);

  gemm_bt<0><<<dim3(DIM/128, T_SEQ/128), 256, 0, stream>>>(Yb, Wob, out, T_SEQ, DIM, DIM);
}

// Round 2
// 325.613 us; speedup vs baseline: 1.2833x; 1.2833x over previous
//
#include <hip/hip_runtime.h>
#include <hip/hip_bf16.h>
#include <cstdint>

#define T_SEQ 2048
#define DIM   1024
#define NHEAD 16
#define NKVH  8
#define HDIM  64
#define QKVN  3584   // 2048 (q) + 1024 (k) + 512 (v)

static constexpr float LAMBDA_INIT_F = 0.3555090675909693f;
static constexpr float ONE_MINUS_LI  = 0.6444909324090307f;

typedef __bf16 bf16x8 __attribute__((ext_vector_type(8)));
typedef float  f32x4  __attribute__((ext_vector_type(4)));

static __device__ __forceinline__ ushort f2bf(float f) {
  union { float f; uint32_t u; } x; x.f = f;
  uint32_t u = x.u;
  uint32_t r = (u + 0x7fffu + ((u >> 16) & 1u)) >> 16;
  return (ushort)r;
}
static __device__ __forceinline__ float bf2f(ushort u) {
  union { uint32_t u; float f; } x; x.u = ((uint32_t)u) << 16; return x.f;
}
static __device__ __forceinline__ f32x4 zero4() {
  f32x4 z = {0.f, 0.f, 0.f, 0.f}; return z;
}
// Load one 8-element A/B fragment for mfma_f32_16x16x32_bf16.
// Per-lane k layout: halves at k = 4*(lane>>4) and k = 16 + 4*(lane>>4).
static __device__ __forceinline__ bf16x8 ldfrag(const ushort* p) {
  union { bf16x8 v; uint2 u[2]; } r;
  r.u[0] = *(const uint2*)(p);
  r.u[1] = *(const uint2*)(p + 16);
  return r.v;
}
// async global->LDS, 16B per lane; lds dest = base + lane*16 (wave-uniform base)
static __device__ __forceinline__ void gll16(const ushort* g, ushort* l) {
  __builtin_amdgcn_global_load_lds(
      (const __attribute__((address_space(1))) uint32_t*)g,
      (__attribute__((address_space(3))) uint32_t*)l, 16, 0, 0);
}

// ---------------- fused fp32->bf16 conversion of x, wq, wk, wv, wo ----------------
__global__ void cvt_all(const float* __restrict__ x,  const float* __restrict__ wq,
                        const float* __restrict__ wk, const float* __restrict__ wv,
                        const float* __restrict__ wo,
                        ushort* __restrict__ xb, ushort* __restrict__ Wb,
                        ushort* __restrict__ Wob) {
  int i = blockIdx.x * 256 + threadIdx.x;   // < 6815744
  if (i < 2097152) {
    xb[i] = f2bf(x[i]);
  } else if (i < 5767168) {
    int j = i - 2097152;                    // index into Wb (wq|wk|wv packed)
    float v;
    if (j < 2097152)      v = wq[j];
    else if (j < 3145728) v = wk[j - 2097152];
    else                  v = wv[j - 3145728];
    Wb[j] = f2bf(v);
  } else {
    int j = i - 5767168;
    Wob[j] = f2bf(wo[j]);
  }
}

__global__ void lam_kernel(const float* __restrict__ lq1, const float* __restrict__ lk1,
                           const float* __restrict__ lq2, const float* __restrict__ lk2,
                           float* __restrict__ lam) {
  int lane = threadIdx.x;  // 64 threads
  float p1 = lq1[lane] * lk1[lane];
  float p2 = lq2[lane] * lk2[lane];
  #pragma unroll
  for (int off = 32; off >= 1; off >>= 1) {
    p1 += __shfl_down(p1, off);
    p2 += __shfl_down(p2, off);
  }
  if (lane == 0) *lam = expf(p1) - expf(p2) + LAMBDA_INIT_F;
}

// ---------------- GEMM: C[M][N] = A[M][K] @ W[N][K]^T, m97 structure ----------------
// 128x128 tile, BK=32, 256 threads (4 waves), global_load_lds staging, linear LDS.
template<int BF16OUT>
__global__ __launch_bounds__(256) void gemm_bt(const ushort* __restrict__ A,
                                               const ushort* __restrict__ W,
                                               void* __restrict__ Cout,
                                               int M, int N, int K) {
  __shared__ ushort As[128 * 32];
  __shared__ ushort Ws[128 * 32];
  const int tid  = threadIdx.x;
  const int lane = tid & 63;
  const int w    = tid >> 6;
  const int wr   = w >> 1, wc = w & 1;
  const int bm   = blockIdx.y * 128, bn = blockIdx.x * 128;
  const int fr   = lane & 15;
  const int fg   = (lane >> 4) * 4;

  f32x4 acc[4][4];
  #pragma unroll
  for (int m = 0; m < 4; ++m)
    #pragma unroll
    for (int n = 0; n < 4; ++n) acc[m][n] = zero4();

  // staging geometry: round s in {0,1}, wave w covers linear elems [(s*4+w)*512, +512)
  const int col  = (lane & 3) * 8;
  const int row0 = w * 16 + (lane >> 2);        // s = 0
  const int row1 = row0 + 64;                   // s = 1
  const ushort* ga0 = A + (size_t)(bm + row0) * K + col;
  const ushort* ga1 = A + (size_t)(bm + row1) * K + col;
  const ushort* gw0 = W + (size_t)(bn + row0) * K + col;
  const ushort* gw1 = W + (size_t)(bn + row1) * K + col;
  ushort* la0 = As + (w * 512);
  ushort* la1 = As + (w * 512) + 2048;
  ushort* lw0 = Ws + (w * 512);
  ushort* lw1 = Ws + (w * 512) + 2048;

  for (int k0 = 0; k0 < K; k0 += 32) {
    gll16(ga0 + k0, la0);
    gll16(ga1 + k0, la1);
    gll16(gw0 + k0, lw0);
    gll16(gw1 + k0, lw1);
    __syncthreads();   // drains vmcnt (global_load_lds) + all waves staged
    bf16x8 af[4], bfr[4];
    #pragma unroll
    for (int m = 0; m < 4; ++m) af[m]  = ldfrag(&As[(wr*64 + m*16 + fr) * 32 + fg]);
    #pragma unroll
    for (int n = 0; n < 4; ++n) bfr[n] = ldfrag(&Ws[(wc*64 + n*16 + fr) * 32 + fg]);
    #pragma unroll
    for (int m = 0; m < 4; ++m)
      #pragma unroll
      for (int n = 0; n < 4; ++n)
        acc[m][n] = __builtin_amdgcn_mfma_f32_16x16x32_bf16(af[m], bfr[n], acc[m][n], 0, 0, 0);
    __syncthreads();   // all reads done before next staging
  }

  #pragma unroll
  for (int m = 0; m < 4; ++m)
    #pragma unroll
    for (int n = 0; n < 4; ++n)
      #pragma unroll
      for (int i = 0; i < 4; ++i) {
        int row = bm + wr*64 + m*16 + fg + i;
        int colg = bn + wc*64 + n*16 + fr;
        float v = acc[m][n][i];
        if (BF16OUT) ((ushort*)Cout)[(size_t)row * N + colg] = f2bf(v);
        else         ((float*)Cout)[(size_t)row * N + colg]  = v;
      }
}

// ---------------- fused RoPE Q, RoPE K, pack V ----------------
// Qr layout [2 comp][16][T][64] (scaled by 1/8), Kr [2 comp][8][T][64], Vt [512][T]
__global__ void reorg(const ushort* __restrict__ QKV, ushort* __restrict__ Qr,
                      ushort* __restrict__ Kr, ushort* __restrict__ Vt,
                      const float* __restrict__ fc, const float* __restrict__ fs) {
  int idx = blockIdx.x * 256 + threadIdx.x;   // < 4194304
  if (idx < 3145728) {
    // RoPE: Q pairs [0, 2097152), K pairs [2097152, 3145728)
    int nheads, col_off;
    ushort* dst;
    float scale;
    int id;
    if (idx < 2097152) { id = idx; nheads = NHEAD; col_off = 0; dst = Qr; scale = 0.125f; }
    else { id = idx - 2097152; nheads = NKVH; col_off = 2048; dst = Kr; scale = 1.0f; }
    int per_t = nheads * 64;
    int t  = id / per_t;
    int r  = id - t * per_t;
    int h  = r >> 6;
    int c2 = (r >> 5) & 1;
    int j  = r & 31;
    int cl = col_off + h * 2 * HDIM + c2 * HDIM + 2 * j;
    float rv = bf2f(QKV[(size_t)t * QKVN + cl]);
    float iv = bf2f(QKV[(size_t)t * QKVN + cl + 1]);
    float c = fc[t * 32 + j], s = fs[t * 32 + j];
    float orr = (rv * c - iv * s) * scale;
    float oi  = (rv * s + iv * c) * scale;
    size_t o = ((size_t)(c2 * nheads + h) * T_SEQ + t) * HDIM + 2 * j;
    dst[o]     = f2bf(orr);
    dst[o + 1] = f2bf(oi);
  } else {
    int id = idx - 3145728;                  // < 1048576
    int t = id & (T_SEQ - 1);
    int rest = id >> 11;                     // kh*64 + d
    Vt[(size_t)rest * T_SEQ + t] = QKV[(size_t)t * QKVN + 3072 + rest];
  }
}

// ---------------- flash attention, 2 streams, Q-in-reg, prefetched K/V ----------------
__global__ __launch_bounds__(256) void attn_kernel(const ushort* __restrict__ Qr,
                                                   const ushort* __restrict__ Kr,
                                                   const ushort* __restrict__ Vt,
                                                   const float* __restrict__ lam_p,
                                                   float* __restrict__ Y) {
  const int qb  = gridDim.x - 1 - blockIdx.x;  // heavy (large-qb) blocks dispatch first
  const int h   = blockIdx.y;
  const int kh  = h >> 1;
  const int tid = threadIdx.x;
  const int lane = tid & 63;
  const int w   = tid >> 6;
  const int fr  = lane & 15;
  const int fg  = (lane >> 4) * 4;

  __shared__ ushort Ks[2][64][72];
  __shared__ ushort Vs[64][72];      // [d][s]
  __shared__ ushort Ps[2][64][72];   // wave-private rows: wave w owns rows [w*16, w*16+16)

  // Q fragments in registers (Q pre-scaled by 1/8)
  bf16x8 qf[2][2];
  {
    const int row = qb * 64 + w * 16 + fr;
    #pragma unroll
    for (int st = 0; st < 2; ++st) {
      const ushort* qp = Qr + ((size_t)(st * NHEAD + h) * T_SEQ + row) * HDIM;
      #pragma unroll
      for (int ks = 0; ks < 2; ++ks) qf[st][ks] = ldfrag(qp + ks * 32 + fg);
    }
  }

  float m_[2][4], l_[2][4];
  f32x4 o_[2][4];
  #pragma unroll
  for (int st = 0; st < 2; ++st) {
    #pragma unroll
    for (int i = 0; i < 4; ++i) { m_[st][i] = -__builtin_inff(); l_[st][i] = 0.f; }
    #pragma unroll
    for (int dn = 0; dn < 4; ++dn) o_[st][dn] = zero4();
  }

  // K/V prefetch registers
  const int srow = tid >> 2, scol = (tid & 3) * 16;
  uint4 kpre[2][2], vpre[2];
  {
    #pragma unroll
    for (int c2 = 0; c2 < 2; ++c2) {
      const ushort* src = Kr + ((size_t)(c2 * NKVH + kh) * T_SEQ + srow) * HDIM + scol;
      kpre[c2][0] = *(const uint4*)src;
      kpre[c2][1] = *(const uint4*)(src + 8);
    }
    const ushort* vsrc = Vt + (size_t)(kh * 64 + srow) * T_SEQ + scol;
    vpre[0] = *(const uint4*)vsrc;
    vpre[1] = *(const uint4*)(vsrc + 8);
  }

  for (int kt = 0; kt <= qb; ++kt) {
    const int kvb = kt * 64;
    __syncthreads();                 // prev iteration's LDS reads complete
    #pragma unroll
    for (int c2 = 0; c2 < 2; ++c2) {
      *(uint4*)&Ks[c2][srow][scol]     = kpre[c2][0];
      *(uint4*)&Ks[c2][srow][scol + 8] = kpre[c2][1];
    }
    *(uint4*)&Vs[srow][scol]     = vpre[0];
    *(uint4*)&Vs[srow][scol + 8] = vpre[1];
    if (kt < qb) {                   // prefetch next tile; latency hides under compute
      const int nb = kvb + 64;
      #pragma unroll
      for (int c2 = 0; c2 < 2; ++c2) {
        const ushort* src = Kr + ((size_t)(c2 * NKVH + kh) * T_SEQ + nb + srow) * HDIM + scol;
        kpre[c2][0] = *(const uint4*)src;
        kpre[c2][1] = *(const uint4*)(src + 8);
      }
      const ushort* vsrc = Vt + (size_t)(kh * 64 + srow) * T_SEQ + nb + scol;
      vpre[0] = *(const uint4*)vsrc;
      vpre[1] = *(const uint4*)(vsrc + 8);
    }
    __syncthreads();                 // staging visible

    #pragma unroll
    for (int st = 0; st < 2; ++st) {
      // S = Q K^T : 16 q-rows x 64 cols per wave
      float sv[4][4];
      #pragma unroll
      for (int n = 0; n < 4; ++n) {
        f32x4 acc = zero4();
        #pragma unroll
        for (int ks = 0; ks < 2; ++ks) {
          bf16x8 bk = ldfrag(&Ks[st][n*16 + fr][ks*32 + fg]);
          acc = __builtin_amdgcn_mfma_f32_16x16x32_bf16(qf[st][ks], bk, acc, 0, 0, 0);
        }
        #pragma unroll
        for (int i = 0; i < 4; ++i) sv[n][i] = acc[i];
      }
      if (kt == qb) {                // causal mask only on diagonal tile
        const int row0 = qb*64 + w*16 + fg;
        #pragma unroll
        for (int n = 0; n < 4; ++n) {
          int colg = kvb + n*16 + fr;
          #pragma unroll
          for (int i = 0; i < 4; ++i)
            if (colg > row0 + i) sv[n][i] = -__builtin_inff();
        }
      }
      // online softmax (16-lane groups own one q-row's 16-col slice per n)
      float pv[4][4];
      #pragma unroll
      for (int i = 0; i < 4; ++i) {
        float mx = fmaxf(fmaxf(sv[0][i], sv[1][i]), fmaxf(sv[2][i], sv[3][i]));
        #pragma unroll
        for (int off = 1; off < 16; off <<= 1) mx = fmaxf(mx, __shfl_xor(mx, off));
        float mnew = fmaxf(m_[st][i], mx);
        float sc = __expf(m_[st][i] - mnew);
        float rs = 0.f;
        #pragma unroll
        for (int n = 0; n < 4; ++n) { float p = __expf(sv[n][i] - mnew); pv[n][i] = p; rs += p; }
        #pragma unroll
        for (int off = 1; off < 16; off <<= 1) rs += __shfl_xor(rs, off);
        l_[st][i] = l_[st][i] * sc + rs;
        m_[st][i] = mnew;
        #pragma unroll
        for (int dn = 0; dn < 4; ++dn) o_[st][dn][i] *= sc;
      }
      #pragma unroll
      for (int n = 0; n < 4; ++n)
        #pragma unroll
        for (int i = 0; i < 4; ++i)
          Ps[st][w*16 + fg + i][n*16 + fr] = f2bf(pv[n][i]);
    }

    // No barrier: Ps rows are wave-private; same-wave DS ops are ordered.
    #pragma unroll
    for (int ks = 0; ks < 2; ++ks) {
      bf16x8 a1 = ldfrag(&Ps[0][w*16 + fr][ks*32 + fg]);
      bf16x8 a2 = ldfrag(&Ps[1][w*16 + fr][ks*32 + fg]);
      #pragma unroll
      for (int dn = 0; dn < 4; ++dn) {
        bf16x8 bv = ldfrag(&Vs[dn*16 + fr][ks*32 + fg]);
        o_[0][dn] = __builtin_amdgcn_mfma_f32_16x16x32_bf16(a1, bv, o_[0][dn], 0, 0, 0);
        o_[1][dn] = __builtin_amdgcn_mfma_f32_16x16x32_bf16(a2, bv, o_[1][dn], 0, 0, 0);
      }
    }
  }

  const float lam = *lam_p;
  #pragma unroll
  for (int dn = 0; dn < 4; ++dn)
    #pragma unroll
    for (int i = 0; i < 4; ++i) {
      int row = qb*64 + w*16 + fg + i;
      int col = h*64 + dn*16 + fr;
      float v = o_[0][dn][i] / l_[0][i] - lam * o_[1][dn][i] / l_[1][i];
      Y[(size_t)row * DIM + col] = v;
    }
}

// ---------------- per-head stats: 256-block partial + finalize ----------------
__global__ __launch_bounds__(256) void stats_partial(const float* __restrict__ Y,
                                                     float* __restrict__ part) {
  const int h = blockIdx.x & 15, sl = blockIdx.x >> 4;   // 16 slices x 128 rows
  float s = 0.f, s2 = 0.f;
  for (int e = threadIdx.x; e < 128 * 64; e += 256) {
    int t = sl * 128 + (e >> 6), d = e & 63;
    float v = Y[(size_t)t * DIM + h * 64 + d];
    s += v; s2 += v * v;
  }
  #pragma unroll
  for (int off = 32; off >= 1; off >>= 1) { s += __shfl_down(s, off); s2 += __shfl_down(s2, off); }
  __shared__ float sb[8];
  int wv = threadIdx.x >> 6, lane = threadIdx.x & 63;
  if (lane == 0) { sb[wv] = s; sb[4 + wv] = s2; }
  __syncthreads();
  if (threadIdx.x == 0) {
    part[blockIdx.x]       = sb[0] + sb[1] + sb[2] + sb[3];
    part[256 + blockIdx.x] = sb[4] + sb[5] + sb[6] + sb[7];
  }
}

__global__ void stats_final(const float* __restrict__ part, float* __restrict__ stat) {
  int hh = threadIdx.x;
  if (hh < 16) {
    float S = 0.f, S2 = 0.f;
    #pragma unroll
    for (int sl = 0; sl < 16; ++sl) { S += part[sl*16 + hh]; S2 += part[256 + sl*16 + hh]; }
    const float N = (float)(T_SEQ * HDIM);
    float mean = S / N;
    float var  = S2 / N - mean * mean;
    stat[hh]      = mean;
    stat[16 + hh] = rsqrtf(var + 1e-5f);
  }
}

__global__ void norm_cvt(const float* __restrict__ Y, const float* __restrict__ stats,
                         ushort* __restrict__ Yb) {
  int idx = blockIdx.x * 256 + threadIdx.x;   // < T*DIM
  int col = idx & (DIM - 1);
  int h = col >> 6;
  float v = (Y[idx] - stats[h]) * stats[16 + h] * ONE_MINUS_LI;
  Yb[idx] = f2bf(v);
}

// ---------------- launch ----------------
extern "C" void kernel_launch(void* const* d_in, const int* in_sizes, int n_in,
                              void* d_out, int out_size, void* d_ws, size_t ws_size,
                              hipStream_t stream) {
  const float* x   = (const float*)d_in[0];
  const float* fc  = (const float*)d_in[1];
  const float* fs  = (const float*)d_in[2];
  const float* wq  = (const float*)d_in[3];
  const float* wk  = (const float*)d_in[4];
  const float* wv  = (const float*)d_in[5];
  const float* wo  = (const float*)d_in[6];
  const float* lq1 = (const float*)d_in[7];
  const float* lk1 = (const float*)d_in[8];
  const float* lq2 = (const float*)d_in[9];
  const float* lk2 = (const float*)d_in[10];
  float* out = (float*)d_out;

  char* ws = (char*)d_ws;
  const size_t OFF_XB   = 0;                         // 2048*1024 bf16
  const size_t OFF_WB   = OFF_XB  + 4194304;         // 3584*1024 bf16
  const size_t OFF_WOB  = OFF_WB  + 7340032;         // 1024*1024 bf16
  const size_t OFF_QKV  = OFF_WOB + 2097152;         // 2048*3584 bf16
  const size_t OFF_QR   = OFF_QKV + 14680064;        // 2*16*2048*64 bf16
  const size_t OFF_KR   = OFF_QR  + 8388608;         // 2*8*2048*64 bf16
  const size_t OFF_VT   = OFF_KR  + 4194304;         // 8*64*2048 bf16
  const size_t OFF_Y    = OFF_VT  + 2097152;         // 2048*1024 f32
  const size_t OFF_YB   = OFF_Y   + 8388608;         // 2048*1024 bf16
  const size_t OFF_ST   = OFF_YB  + 4194304;         // stats + lam + partials

  ushort* xb   = (ushort*)(ws + OFF_XB);
  ushort* Wb   = (ushort*)(ws + OFF_WB);
  ushort* Wob  = (ushort*)(ws + OFF_WOB);
  ushort* QKVb = (ushort*)(ws + OFF_QKV);
  ushort* Qr   = (ushort*)(ws + OFF_QR);
  ushort* Kr   = (ushort*)(ws + OFF_KR);
  ushort* Vt   = (ushort*)(ws + OFF_VT);
  float*  Yf   = (float*)(ws + OFF_Y);
  ushort* Yb   = (ushort*)(ws + OFF_YB);
  float*  stat = (float*)(ws + OFF_ST);
  float*  lamp = stat + 32;
  float*  part = stat + 64;

  cvt_all<<<26624, 256, 0, stream>>>(x, wq, wk, wv, wo, xb, Wb, Wob);
  lam_kernel<<<1, 64, 0, stream>>>(lq1, lk1, lq2, lk2, lamp);

  gemm_bt<1><<<dim3(QKVN/128, T_SEQ/128), 256, 0, stream>>>(xb, Wb, QKVb, T_SEQ, QKVN, DIM);

  reorg<<<16384, 256, 0, stream>>>(QKVb, Qr, Kr, Vt, fc, fs);

  attn_kernel<<<dim3(T_SEQ/64, NHEAD), 256, 0, stream>>>(Qr, Kr, Vt, lamp, Yf);

  stats_partial<<<256, 256, 0, stream>>>(Yf, part);
  stats_final<<<1, 64, 0, stream>>>(part, stat);
  norm_cvt<<<8192, 256, 0, stream>>>(Yf, stat, Yb);

  gemm_bt<0><<<dim3(DIM/128, T_SEQ/128), 256, 0, stream>>>(Yb, Wob, out, T_SEQ, DIM, DIM);
}

// Round 3
// 253.383 us; speedup vs baseline: 1.6492x; 1.2851x over previous
//
#include <hip/hip_runtime.h>
#include <hip/hip_bf16.h>
#include <cstdint>

#define T_SEQ 2048
#define DIM   1024
#define NHEAD 16
#define NKVH  8
#define HDIM  64
#define QKVN  3584   // 2048 (q) + 1024 (k) + 512 (v)

static constexpr float LAMBDA_INIT_F = 0.3555090675909693f;
static constexpr float ONE_MINUS_LI  = 0.6444909324090307f;

typedef __bf16 bf16x8 __attribute__((ext_vector_type(8)));
typedef float  f32x4  __attribute__((ext_vector_type(4)));

static __device__ __forceinline__ ushort f2bf(float f) {
  union { float f; uint32_t u; } x; x.f = f;
  uint32_t u = x.u;
  uint32_t r = (u + 0x7fffu + ((u >> 16) & 1u)) >> 16;
  return (ushort)r;
}
static __device__ __forceinline__ float bf2f(ushort u) {
  union { uint32_t u; float f; } x; x.u = ((uint32_t)u) << 16; return x.f;
}
static __device__ __forceinline__ f32x4 zero4() {
  f32x4 z = {0.f, 0.f, 0.f, 0.f}; return z;
}
// Load one 8-element A/B fragment for mfma_f32_16x16x32_bf16.
// Per-lane k layout: halves at k = 4*(lane>>4) and k = 16 + 4*(lane>>4).
static __device__ __forceinline__ bf16x8 ldfrag(const ushort* p) {
  union { bf16x8 v; uint2 u[2]; } r;
  r.u[0] = *(const uint2*)(p);
  r.u[1] = *(const uint2*)(p + 16);
  return r.v;
}
// async global->LDS, 16B per lane; lds dest = base + lane*16 (wave-uniform base)
static __device__ __forceinline__ void gll16(const ushort* g, ushort* l) {
  __builtin_amdgcn_global_load_lds(
      (const __attribute__((address_space(1))) uint32_t*)g,
      (__attribute__((address_space(3))) uint32_t*)l, 16, 0, 0);
}

// ---------------- fused fp32->bf16 conversion of x, wq, wk, wv, wo ----------------
__global__ void cvt_all(const float* __restrict__ x,  const float* __restrict__ wq,
                        const float* __restrict__ wk, const float* __restrict__ wv,
                        const float* __restrict__ wo,
                        ushort* __restrict__ xb, ushort* __restrict__ Wb,
                        ushort* __restrict__ Wob) {
  int i = blockIdx.x * 256 + threadIdx.x;   // < 6815744
  if (i < 2097152) {
    xb[i] = f2bf(x[i]);
  } else if (i < 5767168) {
    int j = i - 2097152;                    // index into Wb (wq|wk|wv packed)
    float v;
    if (j < 2097152)      v = wq[j];
    else if (j < 3145728) v = wk[j - 2097152];
    else                  v = wv[j - 3145728];
    Wb[j] = f2bf(v);
  } else {
    int j = i - 5767168;
    Wob[j] = f2bf(wo[j]);
  }
}

__global__ void lam_kernel(const float* __restrict__ lq1, const float* __restrict__ lk1,
                           const float* __restrict__ lq2, const float* __restrict__ lk2,
                           float* __restrict__ lam) {
  int lane = threadIdx.x;  // 64 threads
  float p1 = lq1[lane] * lk1[lane];
  float p2 = lq2[lane] * lk2[lane];
  #pragma unroll
  for (int off = 32; off >= 1; off >>= 1) {
    p1 += __shfl_down(p1, off);
    p2 += __shfl_down(p2, off);
  }
  if (lane == 0) *lam = expf(p1) - expf(p2) + LAMBDA_INIT_F;
}

// ---------------- GEMM: C[M][N] = A[M][K] @ W[N][K]^T, m97 structure ----------------
template<int BF16OUT>
__global__ __launch_bounds__(256) void gemm_bt(const ushort* __restrict__ A,
                                               const ushort* __restrict__ W,
                                               void* __restrict__ Cout,
                                               int M, int N, int K) {
  __shared__ ushort As[128 * 32];
  __shared__ ushort Ws[128 * 32];
  const int tid  = threadIdx.x;
  const int lane = tid & 63;
  const int w    = tid >> 6;
  const int wr   = w >> 1, wc = w & 1;
  const int bm   = blockIdx.y * 128, bn = blockIdx.x * 128;
  const int fr   = lane & 15;
  const int fg   = (lane >> 4) * 4;

  f32x4 acc[4][4];
  #pragma unroll
  for (int m = 0; m < 4; ++m)
    #pragma unroll
    for (int n = 0; n < 4; ++n) acc[m][n] = zero4();

  const int col  = (lane & 3) * 8;
  const int row0 = w * 16 + (lane >> 2);
  const int row1 = row0 + 64;
  const ushort* ga0 = A + (size_t)(bm + row0) * K + col;
  const ushort* ga1 = A + (size_t)(bm + row1) * K + col;
  const ushort* gw0 = W + (size_t)(bn + row0) * K + col;
  const ushort* gw1 = W + (size_t)(bn + row1) * K + col;
  ushort* la0 = As + (w * 512);
  ushort* la1 = As + (w * 512) + 2048;
  ushort* lw0 = Ws + (w * 512);
  ushort* lw1 = Ws + (w * 512) + 2048;

  for (int k0 = 0; k0 < K; k0 += 32) {
    gll16(ga0 + k0, la0);
    gll16(ga1 + k0, la1);
    gll16(gw0 + k0, lw0);
    gll16(gw1 + k0, lw1);
    __syncthreads();
    bf16x8 af[4], bfr[4];
    #pragma unroll
    for (int m = 0; m < 4; ++m) af[m]  = ldfrag(&As[(wr*64 + m*16 + fr) * 32 + fg]);
    #pragma unroll
    for (int n = 0; n < 4; ++n) bfr[n] = ldfrag(&Ws[(wc*64 + n*16 + fr) * 32 + fg]);
    #pragma unroll
    for (int m = 0; m < 4; ++m)
      #pragma unroll
      for (int n = 0; n < 4; ++n)
        acc[m][n] = __builtin_amdgcn_mfma_f32_16x16x32_bf16(af[m], bfr[n], acc[m][n], 0, 0, 0);
    __syncthreads();
  }

  #pragma unroll
  for (int m = 0; m < 4; ++m)
    #pragma unroll
    for (int n = 0; n < 4; ++n)
      #pragma unroll
      for (int i = 0; i < 4; ++i) {
        int row = bm + wr*64 + m*16 + fg + i;
        int colg = bn + wc*64 + n*16 + fr;
        float v = acc[m][n][i];
        if (BF16OUT) ((ushort*)Cout)[(size_t)row * N + colg] = f2bf(v);
        else         ((float*)Cout)[(size_t)row * N + colg]  = v;
      }
}

// ---------------- fused RoPE Q, RoPE K, pack V ----------------
__global__ void reorg(const ushort* __restrict__ QKV, ushort* __restrict__ Qr,
                      ushort* __restrict__ Kr, ushort* __restrict__ Vt,
                      const float* __restrict__ fc, const float* __restrict__ fs) {
  int idx = blockIdx.x * 256 + threadIdx.x;   // < 4194304
  if (idx < 3145728) {
    int nheads, col_off;
    ushort* dst;
    float scale;
    int id;
    if (idx < 2097152) { id = idx; nheads = NHEAD; col_off = 0; dst = Qr; scale = 0.125f; }
    else { id = idx - 2097152; nheads = NKVH; col_off = 2048; dst = Kr; scale = 1.0f; }
    int per_t = nheads * 64;
    int t  = id / per_t;
    int r  = id - t * per_t;
    int h  = r >> 6;
    int c2 = (r >> 5) & 1;
    int j  = r & 31;
    int cl = col_off + h * 2 * HDIM + c2 * HDIM + 2 * j;
    float rv = bf2f(QKV[(size_t)t * QKVN + cl]);
    float iv = bf2f(QKV[(size_t)t * QKVN + cl + 1]);
    float c = fc[t * 32 + j], s = fs[t * 32 + j];
    float orr = (rv * c - iv * s) * scale;
    float oi  = (rv * s + iv * c) * scale;
    size_t o = ((size_t)(c2 * nheads + h) * T_SEQ + t) * HDIM + 2 * j;
    dst[o]     = f2bf(orr);
    dst[o + 1] = f2bf(oi);
  } else {
    int id = idx - 3145728;                  // < 1048576
    int t = id & (T_SEQ - 1);
    int rest = id >> 11;                     // kh*64 + d
    Vt[(size_t)rest * T_SEQ + t] = QKV[(size_t)t * QKVN + 3072 + rest];
  }
}

// ---------------- flash attention: swapped QK^T, P fully in-register ----------------
// Lane (fr=lane&15, g=lane>>4) holds, per stream, S[q=fr][key = n*16 + 4g + i]
// which is EXACTLY the PV A-fragment layout -> no P round-trip through LDS.
__global__ __launch_bounds__(256) void attn_kernel(const ushort* __restrict__ Qr,
                                                   const ushort* __restrict__ Kr,
                                                   const ushort* __restrict__ Vt,
                                                   const float* __restrict__ lam_p,
                                                   float* __restrict__ Y) {
  const int bx = blockIdx.x;          // 0..511
  const int h  = bx & 15;
  const int jb = bx >> 4;             // 0..31; pair (jb, jb+16) sums to 32 tiles
  const int qb = (jb < 16) ? (31 - jb) : (jb - 16);
  const int kh = h >> 1;
  const int tid = threadIdx.x;
  const int lane = tid & 63;
  const int w   = tid >> 6;
  const int fr  = lane & 15;
  const int fg  = (lane >> 4) * 4;

  __shared__ ushort Ks[2][64][72];
  __shared__ ushort Vs[64][72];      // [d][s]

  // Q fragments in registers (Q pre-scaled by 1/8); used as B-operand (col = q row).
  bf16x8 qf[2][2];
  {
    const int row = qb * 64 + w * 16 + fr;
    #pragma unroll
    for (int st = 0; st < 2; ++st) {
      const ushort* qp = Qr + ((size_t)(st * NHEAD + h) * T_SEQ + row) * HDIM;
      #pragma unroll
      for (int ks = 0; ks < 2; ++ks) qf[st][ks] = ldfrag(qp + ks * 32 + fg);
    }
  }

  float m_[2], l_[2];
  f32x4 o_[2][4];
  #pragma unroll
  for (int st = 0; st < 2; ++st) {
    m_[st] = -__builtin_inff(); l_[st] = 0.f;
    #pragma unroll
    for (int dn = 0; dn < 4; ++dn) o_[st][dn] = zero4();
  }

  // K/V prefetch registers
  const int srow = tid >> 2, scol = (tid & 3) * 16;
  uint4 kpre[2][2], vpre[2];
  {
    #pragma unroll
    for (int c2 = 0; c2 < 2; ++c2) {
      const ushort* src = Kr + ((size_t)(c2 * NKVH + kh) * T_SEQ + srow) * HDIM + scol;
      kpre[c2][0] = *(const uint4*)src;
      kpre[c2][1] = *(const uint4*)(src + 8);
    }
    const ushort* vsrc = Vt + (size_t)(kh * 64 + srow) * T_SEQ + scol;
    vpre[0] = *(const uint4*)vsrc;
    vpre[1] = *(const uint4*)(vsrc + 8);
  }

  for (int kt = 0; kt <= qb; ++kt) {
    const int kvb = kt * 64;
    __syncthreads();                 // prev iteration's LDS reads complete
    #pragma unroll
    for (int c2 = 0; c2 < 2; ++c2) {
      *(uint4*)&Ks[c2][srow][scol]     = kpre[c2][0];
      *(uint4*)&Ks[c2][srow][scol + 8] = kpre[c2][1];
    }
    *(uint4*)&Vs[srow][scol]     = vpre[0];
    *(uint4*)&Vs[srow][scol + 8] = vpre[1];
    if (kt < qb) {
      const int nb = kvb + 64;
      #pragma unroll
      for (int c2 = 0; c2 < 2; ++c2) {
        const ushort* src = Kr + ((size_t)(c2 * NKVH + kh) * T_SEQ + nb + srow) * HDIM + scol;
        kpre[c2][0] = *(const uint4*)src;
        kpre[c2][1] = *(const uint4*)(src + 8);
      }
      const ushort* vsrc = Vt + (size_t)(kh * 64 + srow) * T_SEQ + nb + scol;
      vpre[0] = *(const uint4*)vsrc;
      vpre[1] = *(const uint4*)(vsrc + 8);
    }
    __syncthreads();                 // staging visible

    bf16x8 pa[2][2];                 // P fragments (A-operand for PV), per stream
    #pragma unroll
    for (int st = 0; st < 2; ++st) {
      // S^T tile: mfma(K rows, Q cols) -> lane holds q=fr, keys n*16+fg+i
      float sv[4][4];
      #pragma unroll
      for (int n = 0; n < 4; ++n) {
        f32x4 acc = zero4();
        #pragma unroll
        for (int ks = 0; ks < 2; ++ks) {
          bf16x8 ak = ldfrag(&Ks[st][n*16 + fr][ks*32 + fg]);
          acc = __builtin_amdgcn_mfma_f32_16x16x32_bf16(ak, qf[st][ks], acc, 0, 0, 0);
        }
        #pragma unroll
        for (int i = 0; i < 4; ++i) sv[n][i] = acc[i];
      }
      if (kt == qb) {                // causal mask only on diagonal tile
        const int qrow = w*16 + fr;  // q - kvb
        #pragma unroll
        for (int n = 0; n < 4; ++n)
          #pragma unroll
          for (int i = 0; i < 4; ++i)
            if (n*16 + fg + i > qrow) sv[n][i] = -__builtin_inff();
      }
      // row reduce: in-lane over 16 values + 2 shfl across g-groups
      float rm = -__builtin_inff();
      #pragma unroll
      for (int n = 0; n < 4; ++n)
        #pragma unroll
        for (int i = 0; i < 4; ++i) rm = fmaxf(rm, sv[n][i]);
      rm = fmaxf(rm, __shfl_xor(rm, 16));
      rm = fmaxf(rm, __shfl_xor(rm, 32));
      float mnew = fmaxf(m_[st], rm);
      float sc = __expf(m_[st] - mnew);
      m_[st] = mnew;
      float rs = 0.f;
      float pvv[4][4];
      #pragma unroll
      for (int n = 0; n < 4; ++n)
        #pragma unroll
        for (int i = 0; i < 4; ++i) {
          float p = __expf(sv[n][i] - mnew);
          pvv[n][i] = p; rs += p;
        }
      rs += __shfl_xor(rs, 16);
      rs += __shfl_xor(rs, 32);
      l_[st] = l_[st] * sc + rs;
      // redistribute rescale factor to O rows (q = fg+i), held by lanes fr=fg+i
      float scs[4];
      #pragma unroll
      for (int i = 0; i < 4; ++i) scs[i] = __shfl(sc, fg + i);
      #pragma unroll
      for (int dn = 0; dn < 4; ++dn)
        #pragma unroll
        for (int i = 0; i < 4; ++i) o_[st][dn][i] *= scs[i];
      // pack P (already in PV A-frag layout: ks half = key blocks 2ks, 2ks+1)
      #pragma unroll
      for (int ks = 0; ks < 2; ++ks)
        #pragma unroll
        for (int n2 = 0; n2 < 2; ++n2)
          #pragma unroll
          for (int i = 0; i < 4; ++i)
            pa[st][ks][n2*4 + i] = (__bf16)pvv[2*ks + n2][i];
    }

    // O += P @ V
    #pragma unroll
    for (int ks = 0; ks < 2; ++ks)
      #pragma unroll
      for (int dn = 0; dn < 4; ++dn) {
        bf16x8 bv = ldfrag(&Vs[dn*16 + fr][ks*32 + fg]);
        o_[0][dn] = __builtin_amdgcn_mfma_f32_16x16x32_bf16(pa[0][ks], bv, o_[0][dn], 0, 0, 0);
        o_[1][dn] = __builtin_amdgcn_mfma_f32_16x16x32_bf16(pa[1][ks], bv, o_[1][dn], 0, 0, 0);
      }
  }

  const float lam = *lam_p;
  float li0[4], li1[4];
  #pragma unroll
  for (int i = 0; i < 4; ++i) {
    li0[i] = __shfl(l_[0], fg + i);
    li1[i] = __shfl(l_[1], fg + i);
  }
  #pragma unroll
  for (int dn = 0; dn < 4; ++dn)
    #pragma unroll
    for (int i = 0; i < 4; ++i) {
      int row = qb*64 + w*16 + fg + i;
      int col = h*64 + dn*16 + fr;
      float v = o_[0][dn][i] / li0[i] - lam * o_[1][dn][i] / li1[i];
      Y[(size_t)row * DIM + col] = v;
    }
}

// ---------------- per-head stats: 256-block partial + finalize ----------------
__global__ __launch_bounds__(256) void stats_partial(const float* __restrict__ Y,
                                                     float* __restrict__ part) {
  const int h = blockIdx.x & 15, sl = blockIdx.x >> 4;
  float s = 0.f, s2 = 0.f;
  for (int e = threadIdx.x; e < 128 * 64; e += 256) {
    int t = sl * 128 + (e >> 6), d = e & 63;
    float v = Y[(size_t)t * DIM + h * 64 + d];
    s += v; s2 += v * v;
  }
  #pragma unroll
  for (int off = 32; off >= 1; off >>= 1) { s += __shfl_down(s, off); s2 += __shfl_down(s2, off); }
  __shared__ float sb[8];
  int wv = threadIdx.x >> 6, lane = threadIdx.x & 63;
  if (lane == 0) { sb[wv] = s; sb[4 + wv] = s2; }
  __syncthreads();
  if (threadIdx.x == 0) {
    part[blockIdx.x]       = sb[0] + sb[1] + sb[2] + sb[3];
    part[256 + blockIdx.x] = sb[4] + sb[5] + sb[6] + sb[7];
  }
}

__global__ void stats_final(const float* __restrict__ part, float* __restrict__ stat) {
  int hh = threadIdx.x;
  if (hh < 16) {
    float S = 0.f, S2 = 0.f;
    #pragma unroll
    for (int sl = 0; sl < 16; ++sl) { S += part[sl*16 + hh]; S2 += part[256 + sl*16 + hh]; }
    const float N = (float)(T_SEQ * HDIM);
    float mean = S / N;
    float var  = S2 / N - mean * mean;
    stat[hh]      = mean;
    stat[16 + hh] = rsqrtf(var + 1e-5f);
  }
}

__global__ void norm_cvt(const float* __restrict__ Y, const float* __restrict__ stats,
                         ushort* __restrict__ Yb) {
  int idx = blockIdx.x * 256 + threadIdx.x;
  int col = idx & (DIM - 1);
  int h = col >> 6;
  float v = (Y[idx] - stats[h]) * stats[16 + h] * ONE_MINUS_LI;
  Yb[idx] = f2bf(v);
}

// ---------------- launch ----------------
extern "C" void kernel_launch(void* const* d_in, const int* in_sizes, int n_in,
                              void* d_out, int out_size, void* d_ws, size_t ws_size,
                              hipStream_t stream) {
  const float* x   = (const float*)d_in[0];
  const float* fc  = (const float*)d_in[1];
  const float* fs  = (const float*)d_in[2];
  const float* wq  = (const float*)d_in[3];
  const float* wk  = (const float*)d_in[4];
  const float* wv  = (const float*)d_in[5];
  const float* wo  = (const float*)d_in[6];
  const float* lq1 = (const float*)d_in[7];
  const float* lk1 = (const float*)d_in[8];
  const float* lq2 = (const float*)d_in[9];
  const float* lk2 = (const float*)d_in[10];
  float* out = (float*)d_out;

  char* ws = (char*)d_ws;
  const size_t OFF_XB   = 0;
  const size_t OFF_WB   = OFF_XB  + 4194304;
  const size_t OFF_WOB  = OFF_WB  + 7340032;
  const size_t OFF_QKV  = OFF_WOB + 2097152;
  const size_t OFF_QR   = OFF_QKV + 14680064;
  const size_t OFF_KR   = OFF_QR  + 8388608;
  const size_t OFF_VT   = OFF_KR  + 4194304;
  const size_t OFF_Y    = OFF_VT  + 2097152;
  const size_t OFF_YB   = OFF_Y   + 8388608;
  const size_t OFF_ST   = OFF_YB  + 4194304;

  ushort* xb   = (ushort*)(ws + OFF_XB);
  ushort* Wb   = (ushort*)(ws + OFF_WB);
  ushort* Wob  = (ushort*)(ws + OFF_WOB);
  ushort* QKVb = (ushort*)(ws + OFF_QKV);
  ushort* Qr   = (ushort*)(ws + OFF_QR);
  ushort* Kr   = (ushort*)(ws + OFF_KR);
  ushort* Vt   = (ushort*)(ws + OFF_VT);
  float*  Yf   = (float*)(ws + OFF_Y);
  ushort* Yb   = (ushort*)(ws + OFF_YB);
  float*  stat = (float*)(ws + OFF_ST);
  float*  lamp = stat + 32;
  float*  part = stat + 64;

  cvt_all<<<26624, 256, 0, stream>>>(x, wq, wk, wv, wo, xb, Wb, Wob);
  lam_kernel<<<1, 64, 0, stream>>>(lq1, lk1, lq2, lk2, lamp);

  gemm_bt<1><<<dim3(QKVN/128, T_SEQ/128), 256, 0, stream>>>(xb, Wb, QKVb, T_SEQ, QKVN, DIM);

  reorg<<<16384, 256, 0, stream>>>(QKVb, Qr, Kr, Vt, fc, fs);

  attn_kernel<<<512, 256, 0, stream>>>(Qr, Kr, Vt, lamp, Yf);

  stats_partial<<<256, 256, 0, stream>>>(Yf, part);
  stats_final<<<1, 64, 0, stream>>>(part, stat);
  norm_cvt<<<8192, 256, 0, stream>>>(Yf, stat, Yb);

  gemm_bt<0><<<dim3(DIM/128, T_SEQ/128), 256, 0, stream>>>(Yb, Wob, out, T_SEQ, DIM, DIM);
}

// Round 4
// 248.251 us; speedup vs baseline: 1.6832x; 1.0207x over previous
//
#include <hip/hip_runtime.h>
#include <hip/hip_bf16.h>
#include <cstdint>

#define T_SEQ 2048
#define DIM   1024
#define NHEAD 16
#define NKVH  8
#define HDIM  64
#define QKVN  3584   // 2048 (q) + 1024 (k) + 512 (v)

static constexpr float LAMBDA_INIT_F = 0.3555090675909693f;
static constexpr float ONE_MINUS_LI  = 0.6444909324090307f;

typedef __bf16 bf16x8 __attribute__((ext_vector_type(8)));
typedef float  f32x4  __attribute__((ext_vector_type(4)));

static __device__ __forceinline__ ushort f2bf(float f) {
  union { float f; uint32_t u; } x; x.f = f;
  uint32_t u = x.u;
  uint32_t r = (u + 0x7fffu + ((u >> 16) & 1u)) >> 16;
  return (ushort)r;
}
static __device__ __forceinline__ float bf2f(ushort u) {
  union { uint32_t u; float f; } x; x.u = ((uint32_t)u) << 16; return x.f;
}
static __device__ __forceinline__ f32x4 zero4() {
  f32x4 z = {0.f, 0.f, 0.f, 0.f}; return z;
}
// Load one 8-element A/B fragment for mfma_f32_16x16x32_bf16.
// Per-lane k layout: halves at k = 4*(lane>>4) and k = 16 + 4*(lane>>4).
static __device__ __forceinline__ bf16x8 ldfrag(const ushort* p) {
  union { bf16x8 v; uint2 u[2]; } r;
  r.u[0] = *(const uint2*)(p);
  r.u[1] = *(const uint2*)(p + 16);
  return r.v;
}
// async global->LDS, 16B per lane; lds dest = base + lane*16 (wave-uniform base)
static __device__ __forceinline__ void gll16(const ushort* g, ushort* l) {
  __builtin_amdgcn_global_load_lds(
      (const __attribute__((address_space(1))) uint32_t*)g,
      (__attribute__((address_space(3))) uint32_t*)l, 16, 0, 0);
}

// ---------------- fused fp32->bf16 conversion (vectorized x4) ----------------
__global__ void cvt_all(const float* __restrict__ x,  const float* __restrict__ wq,
                        const float* __restrict__ wk, const float* __restrict__ wv,
                        const float* __restrict__ wo,
                        ushort* __restrict__ xb, ushort* __restrict__ Wb,
                        ushort* __restrict__ Wob) {
  int g = (blockIdx.x * 256 + threadIdx.x) * 4;   // < 6815744
  float4 v; ushort* dst;
  if (g < 2097152) {
    v = *(const float4*)(x + g); dst = xb + g;
  } else if (g < 5767168) {
    int j = g - 2097152;
    const float* src = (j < 2097152) ? (wq + j)
                     : (j < 3145728) ? (wk + (j - 2097152))
                                     : (wv + (j - 3145728));
    v = *(const float4*)src; dst = Wb + j;
  } else {
    int j = g - 5767168;
    v = *(const float4*)(wo + j); dst = Wob + j;
  }
  ushort4 o4;
  o4.x = f2bf(v.x); o4.y = f2bf(v.y); o4.z = f2bf(v.z); o4.w = f2bf(v.w);
  *(ushort4*)dst = o4;
}

__global__ void lam_kernel(const float* __restrict__ lq1, const float* __restrict__ lk1,
                           const float* __restrict__ lq2, const float* __restrict__ lk2,
                           float* __restrict__ lam) {
  int lane = threadIdx.x;  // 64 threads
  float p1 = lq1[lane] * lk1[lane];
  float p2 = lq2[lane] * lk2[lane];
  #pragma unroll
  for (int off = 32; off >= 1; off >>= 1) {
    p1 += __shfl_down(p1, off);
    p2 += __shfl_down(p2, off);
  }
  if (lane == 0) *lam = expf(p1) - expf(p2) + LAMBDA_INIT_F;
}

// ---------------- GEMM: C[M][N] = A[M][K] @ W[N][K]^T, m97 structure ----------------
template<int BF16OUT>
__global__ __launch_bounds__(256) void gemm_bt(const ushort* __restrict__ A,
                                               const ushort* __restrict__ W,
                                               void* __restrict__ Cout,
                                               int M, int N, int K) {
  __shared__ ushort As[128 * 32];
  __shared__ ushort Ws[128 * 32];
  const int tid  = threadIdx.x;
  const int lane = tid & 63;
  const int w    = tid >> 6;
  const int wr   = w >> 1, wc = w & 1;
  const int bm   = blockIdx.y * 128, bn = blockIdx.x * 128;
  const int fr   = lane & 15;
  const int fg   = (lane >> 4) * 4;

  f32x4 acc[4][4];
  #pragma unroll
  for (int m = 0; m < 4; ++m)
    #pragma unroll
    for (int n = 0; n < 4; ++n) acc[m][n] = zero4();

  const int col  = (lane & 3) * 8;
  const int row0 = w * 16 + (lane >> 2);
  const int row1 = row0 + 64;
  const ushort* ga0 = A + (size_t)(bm + row0) * K + col;
  const ushort* ga1 = A + (size_t)(bm + row1) * K + col;
  const ushort* gw0 = W + (size_t)(bn + row0) * K + col;
  const ushort* gw1 = W + (size_t)(bn + row1) * K + col;
  ushort* la0 = As + (w * 512);
  ushort* la1 = As + (w * 512) + 2048;
  ushort* lw0 = Ws + (w * 512);
  ushort* lw1 = Ws + (w * 512) + 2048;

  for (int k0 = 0; k0 < K; k0 += 32) {
    gll16(ga0 + k0, la0);
    gll16(ga1 + k0, la1);
    gll16(gw0 + k0, lw0);
    gll16(gw1 + k0, lw1);
    __syncthreads();
    bf16x8 af[4], bfr[4];
    #pragma unroll
    for (int m = 0; m < 4; ++m) af[m]  = ldfrag(&As[(wr*64 + m*16 + fr) * 32 + fg]);
    #pragma unroll
    for (int n = 0; n < 4; ++n) bfr[n] = ldfrag(&Ws[(wc*64 + n*16 + fr) * 32 + fg]);
    #pragma unroll
    for (int m = 0; m < 4; ++m)
      #pragma unroll
      for (int n = 0; n < 4; ++n)
        acc[m][n] = __builtin_amdgcn_mfma_f32_16x16x32_bf16(af[m], bfr[n], acc[m][n], 0, 0, 0);
    __syncthreads();
  }

  #pragma unroll
  for (int m = 0; m < 4; ++m)
    #pragma unroll
    for (int n = 0; n < 4; ++n)
      #pragma unroll
      for (int i = 0; i < 4; ++i) {
        int row = bm + wr*64 + m*16 + fg + i;
        int colg = bn + wc*64 + n*16 + fr;
        float v = acc[m][n][i];
        if (BF16OUT) ((ushort*)Cout)[(size_t)row * N + colg] = f2bf(v);
        else         ((float*)Cout)[(size_t)row * N + colg]  = v;
      }
}

// ---------------- fused RoPE Q, RoPE K, pack V (vectorized) ----------------
__global__ void reorg(const ushort* __restrict__ QKV, ushort* __restrict__ Qr,
                      ushort* __restrict__ Kr, ushort* __restrict__ Vt,
                      const float* __restrict__ fc, const float* __restrict__ fs) {
  int idx = blockIdx.x * 256 + threadIdx.x;   // < 917504
  if (idx < 786432) {
    // RoPE, 4 interleaved pairs (8 bf16) per thread
    int nheads, col_off; ushort* dst; float scale; int id;
    if (idx < 524288) { id = idx * 4; nheads = NHEAD; col_off = 0; dst = Qr; scale = 0.125f; }
    else { id = (idx - 524288) * 4; nheads = NKVH; col_off = 2048; dst = Kr; scale = 1.0f; }
    int per_t = nheads * 64;
    int t  = id / per_t;
    int r  = id - t * per_t;
    int hh = r >> 6;
    int c2 = (r >> 5) & 1;
    int j  = r & 31;                      // multiple of 4
    int cl = col_off + hh * 128 + c2 * 64 + 2 * j;
    uint4 raw = *(const uint4*)(QKV + (size_t)t * QKVN + cl);
    const ushort* rp = (const ushort*)&raw;
    float c4[4], s4[4];
    *(float4*)c4 = *(const float4*)(fc + t * 32 + j);
    *(float4*)s4 = *(const float4*)(fs + t * 32 + j);
    ushort outv[8];
    #pragma unroll
    for (int p = 0; p < 4; ++p) {
      float rv = bf2f(rp[2*p]), iv = bf2f(rp[2*p + 1]);
      outv[2*p]     = f2bf((rv * c4[p] - iv * s4[p]) * scale);
      outv[2*p + 1] = f2bf((rv * s4[p] + iv * c4[p]) * scale);
    }
    size_t o = ((size_t)(c2 * nheads + hh) * T_SEQ + t) * HDIM + 2 * j;
    *(uint4*)(dst + o) = *(const uint4*)outv;
  } else {
    // V transpose: 8 t-consecutive elems -> one contiguous store
    int id = (idx - 786432) * 8;           // < 1048576
    int t = id & (T_SEQ - 1);              // multiple of 8
    int rest = id >> 11;                   // kh*64 + d
    ushort outv[8];
    #pragma unroll
    for (int p = 0; p < 8; ++p) outv[p] = QKV[(size_t)(t + p) * QKVN + 3072 + rest];
    *(uint4*)(Vt + (size_t)rest * T_SEQ + t) = *(const uint4*)outv;
  }
}

// ---------------- flash attention: stream-split, swapped QK^T, P in-register ----------
// One block = one (stream, head, 64-row q-block). Writes O/l (fp32) to workspace.
__global__ __launch_bounds__(256) void attn_kernel(const ushort* __restrict__ Qr,
                                                   const ushort* __restrict__ Kr,
                                                   const ushort* __restrict__ Vt,
                                                   float* __restrict__ O) {
  const int bx = blockIdx.x;          // 0..1023, heaviest qb first
  const int h  = bx & 15;
  const int st = (bx >> 4) & 1;
  const int qb = 31 - (bx >> 5);
  const int kh = h >> 1;
  const int tid = threadIdx.x;
  const int lane = tid & 63;
  const int w   = tid >> 6;
  const int fr  = lane & 15;
  const int fg  = (lane >> 4) * 4;

  __shared__ ushort Ks[64][72];
  __shared__ ushort Vs[64][72];      // [d][s]

  // Q fragments (pre-scaled by 1/8); B-operand (col = q row)
  bf16x8 qf[2];
  {
    const int row = qb * 64 + w * 16 + fr;
    const ushort* qp = Qr + ((size_t)(st * NHEAD + h) * T_SEQ + row) * HDIM;
    qf[0] = ldfrag(qp + fg);
    qf[1] = ldfrag(qp + 32 + fg);
  }

  float m_ = -__builtin_inff(), l_ = 0.f;
  f32x4 o_[4];
  #pragma unroll
  for (int dn = 0; dn < 4; ++dn) o_[dn] = zero4();

  // K/V prefetch registers
  const int srow = tid >> 2, scol = (tid & 3) * 16;
  uint4 kpre[2], vpre[2];
  const ushort* ksrc0 = Kr + ((size_t)(st * NKVH + kh) * T_SEQ + srow) * HDIM + scol;
  const ushort* vsrc0 = Vt + (size_t)(kh * 64 + srow) * T_SEQ + scol;
  kpre[0] = *(const uint4*)ksrc0;
  kpre[1] = *(const uint4*)(ksrc0 + 8);
  vpre[0] = *(const uint4*)vsrc0;
  vpre[1] = *(const uint4*)(vsrc0 + 8);

  for (int kt = 0; kt <= qb; ++kt) {
    __syncthreads();                 // prev iteration's LDS reads complete
    *(uint4*)&Ks[srow][scol]     = kpre[0];
    *(uint4*)&Ks[srow][scol + 8] = kpre[1];
    *(uint4*)&Vs[srow][scol]     = vpre[0];
    *(uint4*)&Vs[srow][scol + 8] = vpre[1];
    if (kt < qb) {
      const ushort* ks = ksrc0 + (size_t)(kt + 1) * 64 * HDIM;
      const ushort* vs = vsrc0 + (size_t)(kt + 1) * 64;
      kpre[0] = *(const uint4*)ks;
      kpre[1] = *(const uint4*)(ks + 8);
      vpre[0] = *(const uint4*)vs;
      vpre[1] = *(const uint4*)(vs + 8);
    }
    __syncthreads();                 // staging visible

    // S^T tile: mfma(K rows, Q cols) -> lane holds q=fr, keys n*16+fg+i
    float sv[4][4];
    #pragma unroll
    for (int n = 0; n < 4; ++n) {
      f32x4 acc = zero4();
      #pragma unroll
      for (int ks = 0; ks < 2; ++ks) {
        bf16x8 ak = ldfrag(&Ks[n*16 + fr][ks*32 + fg]);
        acc = __builtin_amdgcn_mfma_f32_16x16x32_bf16(ak, qf[ks], acc, 0, 0, 0);
      }
      #pragma unroll
      for (int i = 0; i < 4; ++i) sv[n][i] = acc[i];
    }
    if (kt == qb) {                  // causal mask only on diagonal tile
      const int qrow = w*16 + fr;
      #pragma unroll
      for (int n = 0; n < 4; ++n)
        #pragma unroll
        for (int i = 0; i < 4; ++i)
          if (n*16 + fg + i > qrow) sv[n][i] = -__builtin_inff();
    }
    // row reduce: in-lane 16 values + 2 shfl across g-groups
    float rm = -__builtin_inff();
    #pragma unroll
    for (int n = 0; n < 4; ++n)
      #pragma unroll
      for (int i = 0; i < 4; ++i) rm = fmaxf(rm, sv[n][i]);
    rm = fmaxf(rm, __shfl_xor(rm, 16));
    rm = fmaxf(rm, __shfl_xor(rm, 32));
    float mnew = fmaxf(m_, rm);
    float sc = __expf(m_ - mnew);
    m_ = mnew;
    float rs = 0.f;
    float pvv[4][4];
    #pragma unroll
    for (int n = 0; n < 4; ++n)
      #pragma unroll
      for (int i = 0; i < 4; ++i) {
        float p = __expf(sv[n][i] - mnew);
        pvv[n][i] = p; rs += p;
      }
    rs += __shfl_xor(rs, 16);
    rs += __shfl_xor(rs, 32);
    l_ = l_ * sc + rs;
    // redistribute rescale to O rows (q = fg+i)
    float scs[4];
    #pragma unroll
    for (int i = 0; i < 4; ++i) scs[i] = __shfl(sc, fg + i);
    #pragma unroll
    for (int dn = 0; dn < 4; ++dn)
      #pragma unroll
      for (int i = 0; i < 4; ++i) o_[dn][i] *= scs[i];
    // pack P (already in PV A-frag layout)
    bf16x8 pa[2];
    #pragma unroll
    for (int ks = 0; ks < 2; ++ks)
      #pragma unroll
      for (int n2 = 0; n2 < 2; ++n2)
        #pragma unroll
        for (int i = 0; i < 4; ++i)
          pa[ks][n2*4 + i] = (__bf16)pvv[2*ks + n2][i];

    // O += P @ V
    #pragma unroll
    for (int ks = 0; ks < 2; ++ks)
      #pragma unroll
      for (int dn = 0; dn < 4; ++dn) {
        bf16x8 bv = ldfrag(&Vs[dn*16 + fr][ks*32 + fg]);
        o_[dn] = __builtin_amdgcn_mfma_f32_16x16x32_bf16(pa[ks], bv, o_[dn], 0, 0, 0);
      }
  }

  float li[4];
  #pragma unroll
  for (int i = 0; i < 4; ++i) li[i] = __shfl(l_, fg + i);
  #pragma unroll
  for (int dn = 0; dn < 4; ++dn)
    #pragma unroll
    for (int i = 0; i < 4; ++i) {
      int row = qb*64 + w*16 + fg + i;
      O[((size_t)(st * NHEAD + h) * T_SEQ + row) * HDIM + dn*16 + fr] = o_[dn][i] / li[i];
    }
}

// ---------------- combine streams + LayerNorm partial sums ----------------
__global__ __launch_bounds__(256) void combine_stats(const float* __restrict__ O,
                                                     const float* __restrict__ lamp,
                                                     float* __restrict__ Yf,
                                                     float* __restrict__ part) {
  const int h = blockIdx.x & 15, sl = blockIdx.x >> 4;
  const float lam = *lamp;
  float s = 0.f, s2 = 0.f;
  for (int e = threadIdx.x; e < 2048; e += 256) {   // 128 rows x 16 float4
    int row = sl * 128 + (e >> 4);
    int d4  = (e & 15) * 4;
    size_t i0 = ((size_t)h * T_SEQ + row) * HDIM + d4;
    size_t i1 = ((size_t)(NHEAD + h) * T_SEQ + row) * HDIM + d4;
    float4 a = *(const float4*)(O + i0);
    float4 b = *(const float4*)(O + i1);
    float4 v;
    v.x = a.x - lam * b.x; v.y = a.y - lam * b.y;
    v.z = a.z - lam * b.z; v.w = a.w - lam * b.w;
    s  += v.x + v.y + v.z + v.w;
    s2 += v.x*v.x + v.y*v.y + v.z*v.z + v.w*v.w;
    *(float4*)(Yf + (size_t)row * DIM + h * 64 + d4) = v;
  }
  #pragma unroll
  for (int off = 32; off >= 1; off >>= 1) { s += __shfl_down(s, off); s2 += __shfl_down(s2, off); }
  __shared__ float sb[8];
  int wv = threadIdx.x >> 6, lane = threadIdx.x & 63;
  if (lane == 0) { sb[wv] = s; sb[4 + wv] = s2; }
  __syncthreads();
  if (threadIdx.x == 0) {
    part[blockIdx.x]       = sb[0] + sb[1] + sb[2] + sb[3];
    part[256 + blockIdx.x] = sb[4] + sb[5] + sb[6] + sb[7];
  }
}

__global__ void stats_final(const float* __restrict__ part, float* __restrict__ stat) {
  int hh = threadIdx.x;
  if (hh < 16) {
    float S = 0.f, S2 = 0.f;
    #pragma unroll
    for (int sl = 0; sl < 16; ++sl) { S += part[sl*16 + hh]; S2 += part[256 + sl*16 + hh]; }
    const float N = (float)(T_SEQ * HDIM);
    float mean = S / N;
    float var  = S2 / N - mean * mean;
    stat[hh]      = mean;
    stat[16 + hh] = rsqrtf(var + 1e-5f);
  }
}

__global__ void norm_cvt(const float* __restrict__ Y, const float* __restrict__ stats,
                         ushort* __restrict__ Yb) {
  int idx = blockIdx.x * 256 + threadIdx.x;
  int col = idx & (DIM - 1);
  int h = col >> 6;
  float v = (Y[idx] - stats[h]) * stats[16 + h] * ONE_MINUS_LI;
  Yb[idx] = f2bf(v);
}

// ---------------- launch ----------------
extern "C" void kernel_launch(void* const* d_in, const int* in_sizes, int n_in,
                              void* d_out, int out_size, void* d_ws, size_t ws_size,
                              hipStream_t stream) {
  const float* x   = (const float*)d_in[0];
  const float* fc  = (const float*)d_in[1];
  const float* fs  = (const float*)d_in[2];
  const float* wq  = (const float*)d_in[3];
  const float* wk  = (const float*)d_in[4];
  const float* wv  = (const float*)d_in[5];
  const float* wo  = (const float*)d_in[6];
  const float* lq1 = (const float*)d_in[7];
  const float* lk1 = (const float*)d_in[8];
  const float* lq2 = (const float*)d_in[9];
  const float* lk2 = (const float*)d_in[10];
  float* out = (float*)d_out;

  char* ws = (char*)d_ws;
  // Layout (bytes). O (16 MB) and Yf (8 MB) reuse regions dead by attn time.
  const size_t OFF_WOB  = 0;                 // 2 MB, live till end
  const size_t OFF_XB   = 2097152;           // 4 MB, dead after gemm1
  const size_t OFF_WB   = 6291456;           // 7 MB, dead after gemm1
  const size_t OFF_QKV  = 13631488;          // 14.68 MB, dead after reorg
  const size_t OFF_QR   = 28311552;          // 8 MB
  const size_t OFF_KR   = 36700160;          // 4 MB
  const size_t OFF_VT   = 40894464;          // 2 MB
  const size_t OFF_O    = OFF_XB;            // 16 MB over xb/Wb/QKV-head (dead)
  const size_t OFF_Y    = 18874368;          // 8 MB over QKV tail (dead)
  const size_t OFF_YB   = 42991616;          // 4 MB
  const size_t OFF_ST   = 47185920;          // stats + lam + partials

  ushort* xb   = (ushort*)(ws + OFF_XB);
  ushort* Wb   = (ushort*)(ws + OFF_WB);
  ushort* Wob  = (ushort*)(ws + OFF_WOB);
  ushort* QKVb = (ushort*)(ws + OFF_QKV);
  ushort* Qr   = (ushort*)(ws + OFF_QR);
  ushort* Kr   = (ushort*)(ws + OFF_KR);
  ushort* Vt   = (ushort*)(ws + OFF_VT);
  float*  Of   = (float*)(ws + OFF_O);
  float*  Yf   = (float*)(ws + OFF_Y);
  ushort* Yb   = (ushort*)(ws + OFF_YB);
  float*  stat = (float*)(ws + OFF_ST);
  float*  lamp = stat + 32;
  float*  part = stat + 64;

  cvt_all<<<6656, 256, 0, stream>>>(x, wq, wk, wv, wo, xb, Wb, Wob);
  lam_kernel<<<1, 64, 0, stream>>>(lq1, lk1, lq2, lk2, lamp);

  gemm_bt<1><<<dim3(QKVN/128, T_SEQ/128), 256, 0, stream>>>(xb, Wb, QKVb, T_SEQ, QKVN, DIM);

  reorg<<<3584, 256, 0, stream>>>(QKVb, Qr, Kr, Vt, fc, fs);

  attn_kernel<<<1024, 256, 0, stream>>>(Qr, Kr, Vt, Of);

  combine_stats<<<256, 256, 0, stream>>>(Of, lamp, Yf, part);
  stats_final<<<1, 64, 0, stream>>>(part, stat);
  norm_cvt<<<8192, 256, 0, stream>>>(Yf, stat, Yb);

  gemm_bt<0><<<dim3(DIM/128, T_SEQ/128), 256, 0, stream>>>(Yb, Wob, out, T_SEQ, DIM, DIM);
}